// Round 2
// baseline (64.691 us; speedup 1.0000x reference)
//
#include <hip/hip_runtime.h>

// LDDMM variational evolve: N-body Gaussian kernel sums, N=8192, D=3, fp32.
// dmom_i = (1/SIG2) * sum_j K_ij * <mom_i,mom_j> * (pos_i - pos_j)
// dpos_i = sum_j K_ij * mom_j
// K_ij = exp(-||pos_i-pos_j||^2 / (2*SIG2)), SIG2 = 0.01 -> exp2(-72.1348*d2)
//
// Inner-loop algebra: d2 = ri + rj - 2<xi,xj>; accumulate S=sum(s), SP=sum(s*xj)
// so dmom_i = 100*(xi*S - SP). LDS holds pre-scaled j-data so the exp arg is a
// pure FMA chain: arg = ci + sum_d xi_d * (144.27*xj_d) + (-72.13*rj).

#define NPTS    8192
#define THREADS 256
#define ILANES  2
#define IBLK    (THREADS * ILANES)   // 512 i's per block

#define A_DOT 144.269504088896f      // 2*50*log2(e)
#define A_R   (-72.134752044448f)    // -50*log2(e)
#define INV_SIG2 100.0f

template <int JBLK, bool ATOMIC>
__global__ __launch_bounds__(THREADS)
void lddmm_main(const float* __restrict__ mom,
                const float* __restrict__ pos,
                float* __restrict__ partial,   // [NJC][6][NPTS] when !ATOMIC
                float* __restrict__ out)       // used when ATOMIC
{
    __shared__ float4 sp[JBLK];   // (A_DOT*x, A_DOT*y, A_DOT*z, A_R*r2)
    __shared__ float4 sm[JBLK];   // (mx, my, mz, 0)

    const int t  = threadIdx.x;
    const int i0 = blockIdx.x * IBLK;
    const int jc = blockIdx.y;
    const int jbase = jc * JBLK;

    // Stage this block's j-chunk into LDS, pre-scaled.
    if (t < JBLK) {
        const int j = jbase + t;
        const float x = pos[3*j+0], y = pos[3*j+1], z = pos[3*j+2];
        const float r2 = x*x + y*y + z*z;
        sp[t] = make_float4(A_DOT*x, A_DOT*y, A_DOT*z, A_R*r2);
        sm[t] = make_float4(mom[3*j+0], mom[3*j+1], mom[3*j+2], 0.0f);
    }
    __syncthreads();

    const int iA = i0 + t;
    const int iB = i0 + THREADS + t;

    const float xA = pos[3*iA+0], yA = pos[3*iA+1], zA = pos[3*iA+2];
    const float pxA = mom[3*iA+0], pyA = mom[3*iA+1], pzA = mom[3*iA+2];
    const float xB = pos[3*iB+0], yB = pos[3*iB+1], zB = pos[3*iB+2];
    const float pxB = mom[3*iB+0], pyB = mom[3*iB+1], pzB = mom[3*iB+2];
    const float ciA = A_R * (xA*xA + yA*yA + zA*zA);
    const float ciB = A_R * (xB*xB + yB*yB + zB*zB);

    // Accumulators: S = sum s, SP = sum s*(A_DOT*xj), ap = sum K*mj
    float SA=0.f, SPAx=0.f, SPAy=0.f, SPAz=0.f, apAx=0.f, apAy=0.f, apAz=0.f;
    float SB=0.f, SPBx=0.f, SPBy=0.f, SPBz=0.f, apBx=0.f, apBy=0.f, apBz=0.f;

    #pragma unroll 4
    for (int j = 0; j < JBLK; ++j) {
        const float4 P = sp[j];   // broadcast ds_read_b128
        const float4 M = sm[j];

        // i = A
        {
            float arg = __builtin_fmaf(xA, P.x, P.w);
            arg = __builtin_fmaf(yA, P.y, arg);
            arg = __builtin_fmaf(zA, P.z, arg);
            const float K = exp2f(arg + ciA);
            const float C = __builtin_fmaf(pzA, M.z, __builtin_fmaf(pyA, M.y, pxA*M.x));
            const float s = K * C;
            SA  += s;
            SPAx = __builtin_fmaf(s, P.x, SPAx);
            SPAy = __builtin_fmaf(s, P.y, SPAy);
            SPAz = __builtin_fmaf(s, P.z, SPAz);
            apAx = __builtin_fmaf(K, M.x, apAx);
            apAy = __builtin_fmaf(K, M.y, apAy);
            apAz = __builtin_fmaf(K, M.z, apAz);
        }
        // i = B
        {
            float arg = __builtin_fmaf(xB, P.x, P.w);
            arg = __builtin_fmaf(yB, P.y, arg);
            arg = __builtin_fmaf(zB, P.z, arg);
            const float K = exp2f(arg + ciB);
            const float C = __builtin_fmaf(pzB, M.z, __builtin_fmaf(pyB, M.y, pxB*M.x));
            const float s = K * C;
            SB  += s;
            SPBx = __builtin_fmaf(s, P.x, SPBx);
            SPBy = __builtin_fmaf(s, P.y, SPBy);
            SPBz = __builtin_fmaf(s, P.z, SPBz);
            apBx = __builtin_fmaf(K, M.x, apBx);
            apBy = __builtin_fmaf(K, M.y, apBy);
            apBz = __builtin_fmaf(K, M.z, apBz);
        }
    }

    // Unscale: sum s*xj = SP / A_DOT; dmom = 100*(xi*S - sum s*xj)
    const float US = INV_SIG2 / A_DOT;   // applied to SP
    const float amAx = INV_SIG2*xA*SA - US*SPAx;
    const float amAy = INV_SIG2*yA*SA - US*SPAy;
    const float amAz = INV_SIG2*zA*SA - US*SPAz;
    const float amBx = INV_SIG2*xB*SB - US*SPBx;
    const float amBy = INV_SIG2*yB*SB - US*SPBy;
    const float amBz = INV_SIG2*zB*SB - US*SPBz;

    if (!ATOMIC) {
        float* base = partial + (size_t)jc * (6 * NPTS);
        base[0*NPTS + iA] = amAx;
        base[1*NPTS + iA] = amAy;
        base[2*NPTS + iA] = amAz;
        base[3*NPTS + iA] = apAx;
        base[4*NPTS + iA] = apAy;
        base[5*NPTS + iA] = apAz;
        base[0*NPTS + iB] = amBx;
        base[1*NPTS + iB] = amBy;
        base[2*NPTS + iB] = amBz;
        base[3*NPTS + iB] = apBx;
        base[4*NPTS + iB] = apBy;
        base[5*NPTS + iB] = apBz;
    } else {
        atomicAdd(&out[3*iA+0], amAx);
        atomicAdd(&out[3*iA+1], amAy);
        atomicAdd(&out[3*iA+2], amAz);
        atomicAdd(&out[3*NPTS + 3*iA+0], apAx);
        atomicAdd(&out[3*NPTS + 3*iA+1], apAy);
        atomicAdd(&out[3*NPTS + 3*iA+2], apAz);
        atomicAdd(&out[3*iB+0], amBx);
        atomicAdd(&out[3*iB+1], amBy);
        atomicAdd(&out[3*iB+2], amBz);
        atomicAdd(&out[3*NPTS + 3*iB+0], apBx);
        atomicAdd(&out[3*NPTS + 3*iB+1], apBy);
        atomicAdd(&out[3*NPTS + 3*iB+2], apBz);
    }
}

template <int NJC>
__global__ __launch_bounds__(256)
void lddmm_reduce(const float* __restrict__ partial, float* __restrict__ out)
{
    const int idx = blockIdx.x * blockDim.x + threadIdx.x;  // 0 .. 6*NPTS-1
    int comp, i;
    if (idx < 3 * NPTS) { i = idx / 3; comp = idx % 3; }            // dmom
    else { const int r = idx - 3 * NPTS; i = r / 3; comp = 3 + r % 3; }  // dpos
    float s = 0.0f;
    #pragma unroll
    for (int jc = 0; jc < NJC; ++jc)
        s += partial[(size_t)jc * (6 * NPTS) + (size_t)comp * NPTS + i];
    out[idx] = s;
}

extern "C" void kernel_launch(void* const* d_in, const int* in_sizes, int n_in,
                              void* d_out, int out_size, void* d_ws, size_t ws_size,
                              hipStream_t stream)
{
    const float* mom = (const float*)d_in[0];
    const float* pos = (const float*)d_in[1];
    float* out = (float*)d_out;
    float* partial = (float*)d_ws;

    const size_t per_jc = (size_t)6 * NPTS * sizeof(float);  // 196608 B

    if (ws_size >= 64 * per_jc) {
        // JBLK=128, NJC=64 -> grid 16x64 = 1024 blocks = 4 blocks/CU
        dim3 grid(NPTS / IBLK, 64);
        lddmm_main<128, false><<<grid, THREADS, 0, stream>>>(mom, pos, partial, out);
        lddmm_reduce<64><<<(6 * NPTS) / 256, 256, 0, stream>>>(partial, out);
    } else if (ws_size >= 32 * per_jc) {
        dim3 grid(NPTS / IBLK, 32);
        lddmm_main<256, false><<<grid, THREADS, 0, stream>>>(mom, pos, partial, out);
        lddmm_reduce<32><<<(6 * NPTS) / 256, 256, 0, stream>>>(partial, out);
    } else {
        hipMemsetAsync(out, 0, (size_t)6 * NPTS * sizeof(float), stream);
        dim3 grid(NPTS / IBLK, 32);
        lddmm_main<256, true><<<grid, THREADS, 0, stream>>>(mom, pos, nullptr, out);
    }
}

// Round 3
// 48.854 us; speedup vs baseline: 1.3242x; 1.3242x over previous
//
#include <hip/hip_runtime.h>

// LDDMM variational evolve: N-body Gaussian kernel sums, N=8192, D=3, fp32.
// dmom_i = (1/SIG2) * sum_j K_ij * <mom_i,mom_j> * (pos_i - pos_j)
// dpos_i = sum_j K_ij * mom_j
// K_ij = exp(-||pos_i-pos_j||^2 / (2*SIG2)), SIG2 = 0.01 -> exp2(-72.1348*d2)
//
// d2 = ri + rj - 2<xi,xj>; LDS holds pre-scaled j-data so the exp arg is a
// pure FMA chain. Accumulate S=sum(s), SP=sum(s*xj_scaled) so
// dmom_i = 100*(xi*S - SP/A_DOT).
// exp MUST be __builtin_amdgcn_exp2f: plain exp2f goes through OCML's
// fixup path (~10 extra VALU ops/call) -- measured flat 48us in R2.

#define NPTS    8192
#define THREADS 256
#define ILANES  2
#define IBLK    (THREADS * ILANES)   // 512 i's per block

#define A_DOT 144.269504088896f      // 2*50*log2(e)
#define A_R   (-72.134752044448f)    // -50*log2(e)
#define INV_SIG2 100.0f

#define EXP2(x) __builtin_amdgcn_exp2f(x)

template <int JBLK, bool ATOMIC>
__global__ __launch_bounds__(THREADS)
void lddmm_main(const float* __restrict__ mom,
                const float* __restrict__ pos,
                float* __restrict__ partial,   // [NJC][6][NPTS] when !ATOMIC
                float* __restrict__ out)       // used when ATOMIC
{
    __shared__ float4 sp[JBLK];   // (A_DOT*x, A_DOT*y, A_DOT*z, A_R*r2)
    __shared__ float4 sm[JBLK];   // (mx, my, mz, 0)

    const int t  = threadIdx.x;
    const int i0 = blockIdx.x * IBLK;
    const int jc = blockIdx.y;
    const int jbase = jc * JBLK;

    if (t < JBLK) {
        const int j = jbase + t;
        const float x = pos[3*j+0], y = pos[3*j+1], z = pos[3*j+2];
        const float r2 = x*x + y*y + z*z;
        sp[t] = make_float4(A_DOT*x, A_DOT*y, A_DOT*z, A_R*r2);
        sm[t] = make_float4(mom[3*j+0], mom[3*j+1], mom[3*j+2], 0.0f);
    }
    __syncthreads();

    const int iA = i0 + t;
    const int iB = i0 + THREADS + t;

    const float xA = pos[3*iA+0], yA = pos[3*iA+1], zA = pos[3*iA+2];
    const float pxA = mom[3*iA+0], pyA = mom[3*iA+1], pzA = mom[3*iA+2];
    const float xB = pos[3*iB+0], yB = pos[3*iB+1], zB = pos[3*iB+2];
    const float pxB = mom[3*iB+0], pyB = mom[3*iB+1], pzB = mom[3*iB+2];
    const float ciA = A_R * (xA*xA + yA*yA + zA*zA);
    const float ciB = A_R * (xB*xB + yB*yB + zB*zB);

    float SA=0.f, SPAx=0.f, SPAy=0.f, SPAz=0.f, apAx=0.f, apAy=0.f, apAz=0.f;
    float SB=0.f, SPBx=0.f, SPBy=0.f, SPBz=0.f, apBx=0.f, apBy=0.f, apBz=0.f;

    #pragma unroll 8
    for (int j = 0; j < JBLK; ++j) {
        const float4 P = sp[j];   // broadcast ds_read_b128
        const float4 M = sm[j];

        // i = A
        {
            float arg = __builtin_fmaf(xA, P.x, ciA + P.w);
            arg = __builtin_fmaf(yA, P.y, arg);
            arg = __builtin_fmaf(zA, P.z, arg);
            const float K = EXP2(arg);
            const float C = __builtin_fmaf(pzA, M.z, __builtin_fmaf(pyA, M.y, pxA*M.x));
            const float s = K * C;
            SA  += s;
            SPAx = __builtin_fmaf(s, P.x, SPAx);
            SPAy = __builtin_fmaf(s, P.y, SPAy);
            SPAz = __builtin_fmaf(s, P.z, SPAz);
            apAx = __builtin_fmaf(K, M.x, apAx);
            apAy = __builtin_fmaf(K, M.y, apAy);
            apAz = __builtin_fmaf(K, M.z, apAz);
        }
        // i = B
        {
            float arg = __builtin_fmaf(xB, P.x, ciB + P.w);
            arg = __builtin_fmaf(yB, P.y, arg);
            arg = __builtin_fmaf(zB, P.z, arg);
            const float K = EXP2(arg);
            const float C = __builtin_fmaf(pzB, M.z, __builtin_fmaf(pyB, M.y, pxB*M.x));
            const float s = K * C;
            SB  += s;
            SPBx = __builtin_fmaf(s, P.x, SPBx);
            SPBy = __builtin_fmaf(s, P.y, SPBy);
            SPBz = __builtin_fmaf(s, P.z, SPBz);
            apBx = __builtin_fmaf(K, M.x, apBx);
            apBy = __builtin_fmaf(K, M.y, apBy);
            apBz = __builtin_fmaf(K, M.z, apBz);
        }
    }

    const float US = INV_SIG2 / A_DOT;
    const float amAx = INV_SIG2*xA*SA - US*SPAx;
    const float amAy = INV_SIG2*yA*SA - US*SPAy;
    const float amAz = INV_SIG2*zA*SA - US*SPAz;
    const float amBx = INV_SIG2*xB*SB - US*SPBx;
    const float amBy = INV_SIG2*yB*SB - US*SPBy;
    const float amBz = INV_SIG2*zB*SB - US*SPBz;

    if (!ATOMIC) {
        float* base = partial + (size_t)jc * (6 * NPTS);
        base[0*NPTS + iA] = amAx;
        base[1*NPTS + iA] = amAy;
        base[2*NPTS + iA] = amAz;
        base[3*NPTS + iA] = apAx;
        base[4*NPTS + iA] = apAy;
        base[5*NPTS + iA] = apAz;
        base[0*NPTS + iB] = amBx;
        base[1*NPTS + iB] = amBy;
        base[2*NPTS + iB] = amBz;
        base[3*NPTS + iB] = apBx;
        base[4*NPTS + iB] = apBy;
        base[5*NPTS + iB] = apBz;
    } else {
        atomicAdd(&out[3*iA+0], amAx);
        atomicAdd(&out[3*iA+1], amAy);
        atomicAdd(&out[3*iA+2], amAz);
        atomicAdd(&out[3*NPTS + 3*iA+0], apAx);
        atomicAdd(&out[3*NPTS + 3*iA+1], apAy);
        atomicAdd(&out[3*NPTS + 3*iA+2], apAz);
        atomicAdd(&out[3*iB+0], amBx);
        atomicAdd(&out[3*iB+1], amBy);
        atomicAdd(&out[3*iB+2], amBz);
        atomicAdd(&out[3*NPTS + 3*iB+0], apBx);
        atomicAdd(&out[3*NPTS + 3*iB+1], apBy);
        atomicAdd(&out[3*NPTS + 3*iB+2], apBz);
    }
}

// Coalesced reduce over planar partials: thread handles 4 consecutive planar
// slots (comp,i) with i fastest -> float4 reads are contiguous per jc-plane.
template <int NJC>
__global__ __launch_bounds__(256)
void lddmm_reduce(const float* __restrict__ partial, float* __restrict__ out)
{
    const int p0 = (blockIdx.x * 256 + threadIdx.x) * 4;  // 0 .. 6*NPTS-1, step 4
    float4 s = make_float4(0.f, 0.f, 0.f, 0.f);
    #pragma unroll
    for (int jc = 0; jc < NJC; ++jc) {
        const float4 v = *reinterpret_cast<const float4*>(
            partial + (size_t)jc * (6 * NPTS) + p0);
        s.x += v.x; s.y += v.y; s.z += v.z; s.w += v.w;
    }
    const int comp = p0 / NPTS;        // constant across the 4 (NPTS % 4 == 0)
    const int i0   = p0 % NPTS;
    const int base = (comp < 3) ? 0 : 3 * NPTS;
    const int c    = (comp < 3) ? comp : comp - 3;
    const float sv[4] = {s.x, s.y, s.z, s.w};
    #pragma unroll
    for (int k = 0; k < 4; ++k)
        out[base + 3 * (i0 + k) + c] = sv[k];
}

extern "C" void kernel_launch(void* const* d_in, const int* in_sizes, int n_in,
                              void* d_out, int out_size, void* d_ws, size_t ws_size,
                              hipStream_t stream)
{
    const float* mom = (const float*)d_in[0];
    const float* pos = (const float*)d_in[1];
    float* out = (float*)d_out;
    float* partial = (float*)d_ws;

    const size_t per_jc = (size_t)6 * NPTS * sizeof(float);  // 196608 B
    const int rblocks = (6 * NPTS) / (256 * 4);              // 48

    if (ws_size >= 128 * per_jc) {
        // JBLK=64, NJC=128 -> 2048 blocks = 8 blocks/CU
        dim3 grid(NPTS / IBLK, 128);
        lddmm_main<64, false><<<grid, THREADS, 0, stream>>>(mom, pos, partial, out);
        lddmm_reduce<128><<<rblocks, 256, 0, stream>>>(partial, out);
    } else if (ws_size >= 64 * per_jc) {
        dim3 grid(NPTS / IBLK, 64);
        lddmm_main<128, false><<<grid, THREADS, 0, stream>>>(mom, pos, partial, out);
        lddmm_reduce<64><<<rblocks, 256, 0, stream>>>(partial, out);
    } else if (ws_size >= 32 * per_jc) {
        dim3 grid(NPTS / IBLK, 32);
        lddmm_main<256, false><<<grid, THREADS, 0, stream>>>(mom, pos, partial, out);
        lddmm_reduce<32><<<rblocks, 256, 0, stream>>>(partial, out);
    } else {
        hipMemsetAsync(out, 0, (size_t)6 * NPTS * sizeof(float), stream);
        dim3 grid(NPTS / IBLK, 32);
        lddmm_main<256, true><<<grid, THREADS, 0, stream>>>(mom, pos, nullptr, out);
    }
}

// Round 4
// 36.187 us; speedup vs baseline: 1.7877x; 1.3500x over previous
//
#include <hip/hip_runtime.h>

// LDDMM variational evolve: N-body Gaussian kernel sums, N=8192, D=3, fp32.
// dmom_i = (1/SIG2) * sum_j K_ij * <mom_i,mom_j> * (pos_i - pos_j)
// dpos_i = sum_j K_ij * mom_j
// K_ij = exp(-||pos_i-pos_j||^2/(2*SIG2)), SIG2=0.01 -> exp2(-72.1348*d2)
//
// d2 = ri + rj - 2<xi,xj>; LDS holds pre-scaled j-data so the exp arg is a
// pure FMA chain. Accumulate S=sum(s), SP=sum(s*xj_scaled) so
// dmom_i = 100*(xi*S - SP/A_DOT).
// exp = __builtin_amdgcn_exp2f (plain exp2f -> OCML fixup path, ~10 extra
// VALU ops/pair; measured flat 48us in R2).
// ILANES=4: R3 showed LDS-pipe co-limit (VALUBusy 61% @ 36% occupancy);
// 2 broadcast ds_read_b128 per j-iter now amortize over 128 VALU-cycles.

#define NPTS    8192
#define THREADS 256
#define ILANES  4
#define IBLK    (THREADS * ILANES)   // 1024 i's per block

#define A_DOT 144.269504088896f      // 2*50*log2(e)
#define A_R   (-72.134752044448f)    // -50*log2(e)
#define INV_SIG2 100.0f

#define EXP2(x) __builtin_amdgcn_exp2f(x)

template <int JBLK, bool ATOMIC>
__global__ __launch_bounds__(THREADS, 4)
void lddmm_main(const float* __restrict__ mom,
                const float* __restrict__ pos,
                float* __restrict__ partial,   // [NJC][6][NPTS] when !ATOMIC
                float* __restrict__ out)       // used when ATOMIC
{
    __shared__ float4 sp[JBLK];   // (A_DOT*x, A_DOT*y, A_DOT*z, A_R*r2)
    __shared__ float4 sm[JBLK];   // (mx, my, mz, 0)

    const int t  = threadIdx.x;
    const int i0 = blockIdx.x * IBLK;
    const int jc = blockIdx.y;
    const int jbase = jc * JBLK;

    if (t < JBLK) {
        const int j = jbase + t;
        const float x = pos[3*j+0], y = pos[3*j+1], z = pos[3*j+2];
        const float r2 = x*x + y*y + z*z;
        sp[t] = make_float4(A_DOT*x, A_DOT*y, A_DOT*z, A_R*r2);
        sm[t] = make_float4(mom[3*j+0], mom[3*j+1], mom[3*j+2], 0.0f);
    }
    __syncthreads();

    // Per-i registers, k = 0..3
    float xi[ILANES], yi[ILANES], zi[ILANES], pxi[ILANES], pyi[ILANES], pzi[ILANES], ci[ILANES];
    float S[ILANES], SPx[ILANES], SPy[ILANES], SPz[ILANES], apx[ILANES], apy[ILANES], apz[ILANES];
    #pragma unroll
    for (int k = 0; k < ILANES; ++k) {
        const int i = i0 + k * THREADS + t;
        xi[k] = pos[3*i+0]; yi[k] = pos[3*i+1]; zi[k] = pos[3*i+2];
        pxi[k] = mom[3*i+0]; pyi[k] = mom[3*i+1]; pzi[k] = mom[3*i+2];
        ci[k] = A_R * (xi[k]*xi[k] + yi[k]*yi[k] + zi[k]*zi[k]);
        S[k]=0.f; SPx[k]=0.f; SPy[k]=0.f; SPz[k]=0.f; apx[k]=0.f; apy[k]=0.f; apz[k]=0.f;
    }

    #pragma unroll 4
    for (int j = 0; j < JBLK; ++j) {
        const float4 P = sp[j];   // broadcast ds_read_b128
        const float4 M = sm[j];
        #pragma unroll
        for (int k = 0; k < ILANES; ++k) {
            float arg = __builtin_fmaf(xi[k], P.x, ci[k] + P.w);
            arg = __builtin_fmaf(yi[k], P.y, arg);
            arg = __builtin_fmaf(zi[k], P.z, arg);
            const float K = EXP2(arg);
            const float C = __builtin_fmaf(pzi[k], M.z,
                              __builtin_fmaf(pyi[k], M.y, pxi[k]*M.x));
            const float s = K * C;
            S[k]  += s;
            SPx[k] = __builtin_fmaf(s, P.x, SPx[k]);
            SPy[k] = __builtin_fmaf(s, P.y, SPy[k]);
            SPz[k] = __builtin_fmaf(s, P.z, SPz[k]);
            apx[k] = __builtin_fmaf(K, M.x, apx[k]);
            apy[k] = __builtin_fmaf(K, M.y, apy[k]);
            apz[k] = __builtin_fmaf(K, M.z, apz[k]);
        }
    }

    const float US = INV_SIG2 / A_DOT;
    #pragma unroll
    for (int k = 0; k < ILANES; ++k) {
        const int i = i0 + k * THREADS + t;
        const float amx = INV_SIG2*xi[k]*S[k] - US*SPx[k];
        const float amy = INV_SIG2*yi[k]*S[k] - US*SPy[k];
        const float amz = INV_SIG2*zi[k]*S[k] - US*SPz[k];
        if (!ATOMIC) {
            float* base = partial + (size_t)jc * (6 * NPTS);
            base[0*NPTS + i] = amx;
            base[1*NPTS + i] = amy;
            base[2*NPTS + i] = amz;
            base[3*NPTS + i] = apx[k];
            base[4*NPTS + i] = apy[k];
            base[5*NPTS + i] = apz[k];
        } else {
            atomicAdd(&out[3*i+0], amx);
            atomicAdd(&out[3*i+1], amy);
            atomicAdd(&out[3*i+2], amz);
            atomicAdd(&out[3*NPTS + 3*i+0], apx[k]);
            atomicAdd(&out[3*NPTS + 3*i+1], apy[k]);
            atomicAdd(&out[3*NPTS + 3*i+2], apz[k]);
        }
    }
}

// Coalesced reduce over planar partials: thread handles 4 consecutive planar
// slots (comp,i) with i fastest -> float4 reads are contiguous per jc-plane.
template <int NJC>
__global__ __launch_bounds__(256)
void lddmm_reduce(const float* __restrict__ partial, float* __restrict__ out)
{
    const int p0 = (blockIdx.x * 256 + threadIdx.x) * 4;  // 0 .. 6*NPTS-1, step 4
    float4 s = make_float4(0.f, 0.f, 0.f, 0.f);
    #pragma unroll
    for (int jc = 0; jc < NJC; ++jc) {
        const float4 v = *reinterpret_cast<const float4*>(
            partial + (size_t)jc * (6 * NPTS) + p0);
        s.x += v.x; s.y += v.y; s.z += v.z; s.w += v.w;
    }
    const int comp = p0 / NPTS;        // constant across the 4 (NPTS % 4 == 0)
    const int i0   = p0 % NPTS;
    const int base = (comp < 3) ? 0 : 3 * NPTS;
    const int c    = (comp < 3) ? comp : comp - 3;
    const float sv[4] = {s.x, s.y, s.z, s.w};
    #pragma unroll
    for (int k = 0; k < 4; ++k)
        out[base + 3 * (i0 + k) + c] = sv[k];
}

extern "C" void kernel_launch(void* const* d_in, const int* in_sizes, int n_in,
                              void* d_out, int out_size, void* d_ws, size_t ws_size,
                              hipStream_t stream)
{
    const float* mom = (const float*)d_in[0];
    const float* pos = (const float*)d_in[1];
    float* out = (float*)d_out;
    float* partial = (float*)d_ws;

    const size_t per_jc = (size_t)6 * NPTS * sizeof(float);  // 196608 B
    const int rblocks = (6 * NPTS) / (256 * 4);              // 48

    if (ws_size >= 128 * per_jc) {
        // JBLK=64, NJC=128 -> grid 8x128 = 1024 blocks = 4 blocks/CU
        dim3 grid(NPTS / IBLK, 128);
        lddmm_main<64, false><<<grid, THREADS, 0, stream>>>(mom, pos, partial, out);
        lddmm_reduce<128><<<rblocks, 256, 0, stream>>>(partial, out);
    } else if (ws_size >= 64 * per_jc) {
        dim3 grid(NPTS / IBLK, 64);
        lddmm_main<128, false><<<grid, THREADS, 0, stream>>>(mom, pos, partial, out);
        lddmm_reduce<64><<<rblocks, 256, 0, stream>>>(partial, out);
    } else if (ws_size >= 32 * per_jc) {
        dim3 grid(NPTS / IBLK, 32);
        lddmm_main<256, false><<<grid, THREADS, 0, stream>>>(mom, pos, partial, out);
        lddmm_reduce<32><<<rblocks, 256, 0, stream>>>(partial, out);
    } else {
        hipMemsetAsync(out, 0, (size_t)6 * NPTS * sizeof(float), stream);
        dim3 grid(NPTS / IBLK, 32);
        lddmm_main<256, true><<<grid, THREADS, 0, stream>>>(mom, pos, nullptr, out);
    }
}